// Round 9
// baseline (150.461 us; speedup 1.0000x reference)
//
#include <hip/hip_runtime.h>
#include <hip/hip_bf16.h>
#include <math.h>
#include <stdint.h>

// ---------------------------------------------------------------------------
// SCF_GRUCell round 9: register-MLP accum.
// R8 ablation: pure float4 streams over this same data run at ~3 TB/s in BOTH
// grid geometries => the ~400 GB/s pacing of R1-R7 was per-wave load-in-flight
// starvation (slow variants had VGPR=8..32; consume forced serial load-use).
// Fix: 256-thr blocks with __launch_bounds__(256,4) (<=128 VGPR); each wave
// loads a 64-row chunk as 12 independent coalesced 1KB float4 loads into
// static registers (12KB in flight/wave), THEN consumes into the LDS
// histogram. Store-only slot epilogue (proven free), parallel combine, fc, gru.
//
// ws float layout:
//   [0,48)              fsp
//   [4096,104448)       stage[32][3136]
//   [104448,+P*3200)    slots (3072 sums + 64 cnts each)
//   after slots:        binrow[n] bytes (bin per row; 64 = masked)
// ---------------------------------------------------------------------------

#define NBINS 64
#define ROWS 65
#define PAD 49
#define ENT 3136
#define SLOT 3200
#define GROUPS 32
#define FSP_OFF 0
#define STAGE_OFF 4096
#define SLOT_OFF (STAGE_OFF + GROUPS * ENT)   // 104448
#define NBLK 256

__global__ __launch_bounds__(1024) void init_slots_kernel(
    float* __restrict__ slots, int total)
{
    int i = blockIdx.x * 1024 + threadIdx.x;
    int stride = gridDim.x * 1024;
    for (int k = i; k < total; k += stride) slots[k] = 0.0f;
}

__global__ __launch_bounds__(1024) void bin_kernel(
    const float2* __restrict__ loc_others,
    const float*  __restrict__ loc_agent,
    const int*    __restrict__ loc_other_index,
    uint8_t* __restrict__ binrow,
    int n)
{
    int i = blockIdx.x * 1024 + threadIdx.x;
    if (i >= n) return;
    const float ax = loc_agent[0];
    const float ay = loc_agent[1];
    float2 p = loc_others[i];
    float cx = p.x - ax;
    float cy = p.y - ay;
    float d = sqrtf(cx * cx + cy * cy);
    int bin = NBINS;  // dummy (masked)
    if (d >= 0.5f && d <= 40.0f) {
        float ac = acosf(fminf(fmaxf(cx / d, -1.0f), 1.0f));
        float theta = (cy < 0.0f) ? (6.283185307179586f - ac) : ac;
        float uf = floorf((d - 0.5f) / 4.9375f);           // RADIUS_STEP
        float vf = floorf(theta / 0.7853981633974483f);    // THETA_STEP
        int u = (int)fminf(fmaxf(uf, 0.0f), 7.0f);
        int v = (int)fminf(fmaxf(vf, 0.0f), 7.0f);
        bin = u * 8 + v;
    }
    binrow[loc_other_index[i]] = (uint8_t)bin;
}

// 256 threads = 4 waves. Each wave: 64-row chunk = 768 float4 = 12 coalesced
// 1KB loads, all issued into static registers before any consume.
__global__ __launch_bounds__(256, 4) void accum_kernel(
    const float4*  __restrict__ hflat,     // hiddens as float4[n*12]
    const uint8_t* __restrict__ binrow,    // [n]
    float* __restrict__ slots,             // [P][SLOT]
    int nf4, int P, int direct)
{
    __shared__ float s_sum[ROWS * PAD];    // 12.7 KB (row 64 = masked dummy)
    for (int k = threadIdx.x; k < ROWS * PAD; k += 256) s_sum[k] = 0.0f;
    __syncthreads();

    const int lane = threadIdx.x & 63;
    const int wave = (blockIdx.x * 256 + threadIdx.x) >> 6;
    const int nwaves = (gridDim.x * 256) >> 6;
    const int nchunks = (nf4 + 767) / 768;

    for (int c = wave; c < nchunks; c += nwaves) {
        const int cb = c * 768;

        // Phase 1: 12 independent coalesced 16B loads -> static registers.
        float4 h[12];
        int idx[12];
#pragma unroll
        for (int i = 0; i < 12; ++i) {
            int j = cb + i * 64 + lane;
            idx[i] = (j < nf4) ? j : 0;
            h[i] = hflat[idx[i]];
        }
        // Phase 1b: 12 independent binrow byte loads (L1-resident lines).
        int bb[12];
#pragma unroll
        for (int i = 0; i < 12; ++i) {
            unsigned row = (unsigned)idx[i] / 12u;
            bb[i] = binrow[row];
        }

        // Phase 2: consume into shared histogram.
#pragma unroll
        for (int i = 0; i < 12; ++i) {
            unsigned j = (unsigned)idx[i];
            unsigned row = j / 12u;
            unsigned ph = j - row * 12u;
            bool ok = (cb + i * 64 + lane) < nf4;
            if (ok) {
                float* dst = s_sum + bb[i] * PAD + ph * 4;
                unsafeAtomicAdd(dst + 0, h[i].x);
                unsafeAtomicAdd(dst + 1, h[i].y);
                unsafeAtomicAdd(dst + 2, h[i].z);
                unsafeAtomicAdd(dst + 3, h[i].w);
                if (ph == 0u)
                    unsafeAtomicAdd(s_sum + bb[i] * PAD + 48, 1.0f);  // row count
            }
        }
    }
    __syncthreads();

    // Epilogue: plain coalesced stores to this block's private slot.
    float* dst = slots + (size_t)(blockIdx.x % P) * SLOT;
    if (direct) {
        for (int k = threadIdx.x; k < 3072; k += 256) {
            int b = k / 48;
            int j = k - b * 48;
            dst[k] = s_sum[b * PAD + j];
        }
        if (threadIdx.x < NBINS)
            dst[3072 + threadIdx.x] = s_sum[threadIdx.x * PAD + 48];
    } else {
        for (int k = threadIdx.x; k < 3072; k += 256) {
            int b = k / 48;
            int j = k - b * 48;
            float v = s_sum[b * PAD + j];
            if (v != 0.0f) unsafeAtomicAdd(&dst[k], v);
        }
        if (threadIdx.x < NBINS) {
            float v = s_sum[threadIdx.x * PAD + 48];
            if (v != 0.0f) unsafeAtomicAdd(&dst[3072 + threadIdx.x], v);
        }
    }
}

__global__ __launch_bounds__(1024) void combine_kernel(
    const float* __restrict__ slots,   // [P][SLOT]
    float* __restrict__ stage,         // [GROUPS][ENT]
    int P)
{
    int t = blockIdx.x * 1024 + threadIdx.x;
    if (t >= GROUPS * ENT) return;
    unsigned g = (unsigned)t / (unsigned)ENT;
    unsigned k = (unsigned)t - g * ENT;
    int chunk = (P + GROUPS - 1) / GROUPS;
    int s0 = g * chunk;
    int s1 = s0 + chunk; if (s1 > P) s1 = P;
    float s = 0.0f;
#pragma unroll 4
    for (int b = s0; b < s1; ++b) s += slots[(size_t)b * SLOT + k];
    stage[t] = s;
}

__global__ __launch_bounds__(256) void fc_kernel(
    const float* __restrict__ W_fc,    // [48][3072]
    const float* __restrict__ b_fc,    // [48]
    const float* __restrict__ stage,   // [GROUPS][ENT]
    float* __restrict__ fsp)           // [48]
{
    __shared__ float s_cnt[NBINS];
    if (threadIdx.x < NBINS) {
        float c = 0.0f;
#pragma unroll
        for (int g = 0; g < GROUPS; ++g) c += stage[g * ENT + 3072 + threadIdx.x];
        s_cnt[threadIdx.x] = c;
    }
    __syncthreads();

    int r = blockIdx.x;
    const float* w = W_fc + (size_t)r * (NBINS * 48);
    float partial = 0.0f;
    for (int k = threadIdx.x; k < NBINS * 48; k += 256) {
        float s = 0.0f;
#pragma unroll
        for (int g = 0; g < GROUPS; ++g) s += stage[g * ENT + k];
        float c = s_cnt[k / 48];
        float sp = (c > 1.0f) ? (s / c) : s;
        partial += w[k] * sp;
    }
    for (int off = 32; off >= 1; off >>= 1) partial += __shfl_down(partial, off, 64);
    __shared__ float red[4];
    if ((threadIdx.x & 63) == 0) red[threadIdx.x >> 6] = partial;
    __syncthreads();
    if (threadIdx.x == 0) {
        float s = red[0] + red[1] + red[2] + red[3];
        fsp[r] = fmaxf(s + b_fc[r], 0.0f);
    }
}

__global__ void gru_kernel(
    const float* __restrict__ feature_img,
    const float* __restrict__ loc_agent,
    const float* __restrict__ f_vel,
    const float* __restrict__ fsp,
    const float* __restrict__ hidden,
    const float* __restrict__ w_iz, const float* __restrict__ w_hz,
    const float* __restrict__ b_iz, const float* __restrict__ b_hz,
    const float* __restrict__ w_in, const float* __restrict__ w_hn,
    const float* __restrict__ b_in, const float* __restrict__ b_hn,
    float* __restrict__ out)
{
    int l = threadIdx.x;  // one wave
    int u0 = 40 - (int)loc_agent[1];
    int v0 = (int)loc_agent[0];
    int pix = u0 * 80 + v0;

    float pz = 0.0f, pn = 0.0f;
    for (int e = l; e < 96; e += 64) {
        float x;
        if (e < 32)      x = feature_img[e * 6400 + pix];
        else if (e < 48) x = f_vel[e - 32];
        else             x = fsp[e - 48];
        pz += x * w_iz[e];
        pn += x * w_in[e];
    }
    if (l < 48) {
        float h = hidden[l];
        pz += h * w_hz[l];
        pn += h * w_hn[l];
    }
    for (int off = 32; off >= 1; off >>= 1) {
        pz += __shfl_xor(pz, off, 64);
        pn += __shfl_xor(pn, off, 64);
    }
    float zt = 1.0f / (1.0f + expf(-(pz + b_iz[0] + b_hz[0])));
    float nt = tanhf(pn + b_in[0] + b_hn[0]);
    if (l < 48) out[l] = (1.0f - zt) * nt + zt * hidden[l];
}

extern "C" void kernel_launch(void* const* d_in, const int* in_sizes, int n_in,
                              void* d_out, int out_size, void* d_ws, size_t ws_size,
                              hipStream_t stream) {
    const float* loc_agent       = (const float*)d_in[0];
    const float* loc_others      = (const float*)d_in[1];
    const int*   loc_other_index = (const int*)d_in[2];
    const float* feature_img     = (const float*)d_in[3];
    const float* f_vel           = (const float*)d_in[4];
    const float* hiddens         = (const float*)d_in[5];
    const float* hidden          = (const float*)d_in[6];
    const float* W_fc            = (const float*)d_in[7];
    const float* b_fc            = (const float*)d_in[8];
    // d_in[9..12] dead (rt gate)
    const float* w_iz            = (const float*)d_in[13];
    const float* w_hz            = (const float*)d_in[14];
    const float* b_iz            = (const float*)d_in[15];
    const float* b_hz            = (const float*)d_in[16];
    const float* w_in            = (const float*)d_in[17];
    const float* w_hn            = (const float*)d_in[18];
    const float* b_in            = (const float*)d_in[19];
    const float* b_hn            = (const float*)d_in[20];

    float* ws    = (float*)d_ws;
    float* fsp   = ws + FSP_OFF;
    float* stage = ws + STAGE_OFF;
    float* slots = ws + SLOT_OFF;
    float* out   = (float*)d_out;

    int n = in_sizes[2];            // 400000
    int nf4 = n * 12;               // 4.8M float4
    long nwords = (n + 3) / 4;      // binrow u32 words

    long wfloats = (long)(ws_size / 4);
    long avail = (wfloats - SLOT_OFF - nwords) / SLOT;
    int P = (int)(avail < 1 ? 1 : (avail > NBLK ? NBLK : avail));
    int direct = (P == NBLK) ? 1 : 0;
    uint8_t* binrow = (uint8_t*)(ws + SLOT_OFF + (size_t)P * SLOT);

    if (!direct) {
        int total = P * SLOT;
        hipLaunchKernelGGL(init_slots_kernel, dim3((total + 1023) / 1024),
                           dim3(1024), 0, stream, slots, total);
    }
    hipLaunchKernelGGL(bin_kernel, dim3((n + 1023) / 1024), dim3(1024), 0, stream,
                       (const float2*)loc_others, loc_agent, loc_other_index,
                       binrow, n);
    hipLaunchKernelGGL(accum_kernel, dim3(NBLK), dim3(256), 0, stream,
                       (const float4*)hiddens, binrow, slots, nf4, P, direct);
    hipLaunchKernelGGL(combine_kernel, dim3((GROUPS * ENT + 1023) / 1024), dim3(1024), 0, stream,
                       slots, stage, P);
    hipLaunchKernelGGL(fc_kernel, dim3(48), dim3(256), 0, stream,
                       W_fc, b_fc, stage, fsp);
    hipLaunchKernelGGL(gru_kernel, dim3(1), dim3(64), 0, stream,
                       feature_img, loc_agent, f_vel, fsp, hidden,
                       w_iz, w_hz, b_iz, b_hz, w_in, w_hn, b_in, b_hn, out);
}